// Round 1
// baseline (261.940 us; speedup 1.0000x reference)
//
#include <hip/hip_runtime.h>

#define N_E   1024
#define EDIM  256
#define BB    16
#define TT    1024
#define NROW  (BB*TT)        /* 16384 */
#define NCOL  1025
#define NPAD  1152           /* 9*128 */
#define PERS  (0.1f/1024.0f)
#define EPSC  (1e-6f/1024.0f)

/* d_out layout (float32): z_q [0,4194304) | loss 4194304 | ind [4194305,+16384) | v 4210689 */
#define OUT_LOSS 4194304
#define OUT_IDX  4194305
#define OUT_V    4210689

/* ws layout (bytes) */
#define WS_ZB   0ull                               /* 16384*256*2  = 8388608  */
#define WS_BBF  8388608ull                         /* 1152*256*2   = 589824   */
#define WS_BSQ  8978432ull                         /* 1152*4       = 4608     */
#define WS_E    8983552ull                         /* 16384*1152*4 = 75497472 */
#define WS_IND  84481024ull                        /* 16384*4                 */
#define WS_PART 84546560ull                        /* 16384*4                 */

typedef __attribute__((ext_vector_type(8))) short short8;
typedef __attribute__((ext_vector_type(4))) float floatx4;

__device__ __forceinline__ unsigned short f2bf(float f) {
    unsigned int u = __float_as_uint(f);
    u = (u + 0x7fffu + ((u >> 16) & 1u)) >> 16;   /* RNE */
    return (unsigned short)u;
}

/* ---------------- K0: convert z/book -> bf16, compute bsq (fp32) ---------------- */
__global__ __launch_bounds__(256) void k0_prep(const float* __restrict__ z,
                                               const float* __restrict__ book,
                                               unsigned short* __restrict__ zb,
                                               unsigned short* __restrict__ bb,
                                               float* __restrict__ bsq) {
    int bx = blockIdx.x, tid = threadIdx.x;
    if (bx < 4096) {                     /* z: 4096 blocks * 256 thr * 4 floats */
        float4 v = ((const float4*)z)[bx * 256 + tid];
        size_t o = ((size_t)bx * 256 + tid) * 4;
        zb[o + 0] = f2bf(v.x); zb[o + 1] = f2bf(v.y);
        zb[o + 2] = f2bf(v.z); zb[o + 3] = f2bf(v.w);
    } else {                             /* book rows, padded to 1152 with zeros */
        int row = bx - 4096;             /* 0..1151 */
        float v = (row < NCOL) ? book[(size_t)row * EDIM + tid] : 0.0f;
        bb[(size_t)row * EDIM + tid] = f2bf(v);
        __shared__ float sd[256];
        sd[tid] = v * v;
        __syncthreads();
        for (int s = 128; s > 0; s >>= 1) { if (tid < s) sd[tid] += sd[tid + s]; __syncthreads(); }
        if (tid == 0) bsq[row] = sd[0];
    }
}

/* ---------------- K1: e[r][n] = bsq[n] - 2 * dot(z[r], book[n])  (bf16 MFMA) ---- */
__global__ __launch_bounds__(256) void k1_gemm(const unsigned short* __restrict__ zb,
                                               const unsigned short* __restrict__ bb,
                                               const float* __restrict__ bsq,
                                               float* __restrict__ e) {
    int tid = threadIdx.x;
    int lane = tid & 63, w = tid >> 6;
    int mBase = blockIdx.x * 128 + (w >> 1) * 64;
    int nBase = blockIdx.y * 128 + (w & 1) * 64;
    int r = lane & 15, q = lane >> 4;

    floatx4 acc[4][4];
    #pragma unroll
    for (int i = 0; i < 4; i++)
        #pragma unroll
        for (int j = 0; j < 4; j++) acc[i][j] = (floatx4){0.f, 0.f, 0.f, 0.f};

    const short8* A = (const short8*)zb;   /* row stride 256 bf16 = 32 short8 */
    const short8* Bm = (const short8*)bb;

    #pragma unroll
    for (int ks = 0; ks < 8; ks++) {
        int k8 = ks * 4 + q;               /* short8 index in row: (ks*32+q*8)/8 */
        short8 a[4], b[4];
        #pragma unroll
        for (int i = 0; i < 4; i++) a[i] = A[(size_t)(mBase + i * 16 + r) * 32 + k8];
        #pragma unroll
        for (int j = 0; j < 4; j++) b[j] = Bm[(size_t)(nBase + j * 16 + r) * 32 + k8];
        #pragma unroll
        for (int i = 0; i < 4; i++)
            #pragma unroll
            for (int j = 0; j < 4; j++)
                acc[i][j] = __builtin_amdgcn_mfma_f32_16x16x32_bf16(a[i], b[j], acc[i][j], 0, 0, 0);
    }

    float bsql[4];
    #pragma unroll
    for (int j = 0; j < 4; j++) bsql[j] = bsq[nBase + j * 16 + r];

    #pragma unroll
    for (int i = 0; i < 4; i++)
        #pragma unroll
        for (int rr = 0; rr < 4; rr++) {
            int m = mBase + i * 16 + q * 4 + rr;
            float* erow = e + (size_t)m * NPAD;
            #pragma unroll
            for (int j = 0; j < 4; j++)
                erow[nBase + j * 16 + r] = fmaf(-2.0f, acc[i][j][rr], bsql[j]);
        }
}

/* ---------------- K2: serial neighbor scan, one block per batch row ------------
   Phase A (4 waves): fp32 argmin of d[b,0,:] reference-style.
   Phase B (wave 0): integer-scan formulation. stay <=> kk <= q, coe = kk*P,
   q = trunc(m/P) precomputed per (t, col) vectorized.
   SCHEDULING: the per-chunk pipeline is
     [issue 62 loads for chunk c+1] | sched_barrier | [31-step serial chain on
     q[] of chunk c] | sched_barrier | [wait loads, compute q[] for c+1].
   The sched_barrier(0) fences pin this order at codegen: without them the
   compiler sank the loads past the chain (VGPR_Count 68 proves Av/Bv were not
   live across it), serializing ~900cy of L3/HBM latency with the chain.      */
__global__ __launch_bounds__(256, 1) void k2_scan(const float* __restrict__ z,
                                                  const float* __restrict__ book,
                                                  const float* __restrict__ bsq,
                                                  const float* __restrict__ e,
                                                  int* __restrict__ wind) {
    int b = blockIdx.x, tid = threadIdx.x;
    int lane = tid & 63, w = tid >> 6;

    const float4* zr = (const float4*)(z + (size_t)b * TT * EDIM);  /* t=0 row */
    float4 zv = zr[lane];
    float s = zv.x * zv.x + zv.y * zv.y + zv.z * zv.z + zv.w * zv.w;
    #pragma unroll
    for (int off = 32; off; off >>= 1) s += __shfl_xor(s, off, 64);
    float zsq = s;

    float best = 3.4e38f; int bidx = 0;
    for (int wi = w; wi < 17; wi += 4) {
        int n = wi * 64 + lane;
        if (n < NCOL) {
            const float4* br = (const float4*)(book + (size_t)n * EDIM);
            float c0 = 0.f, c1 = 0.f, c2 = 0.f, c3 = 0.f;
            #pragma unroll 8
            for (int k = 0; k < 64; k++) {
                float4 bo = br[k]; float4 za = zr[k];
                c0 = fmaf(za.x, bo.x, c0); c1 = fmaf(za.y, bo.y, c1);
                c2 = fmaf(za.z, bo.z, c2); c3 = fmaf(za.w, bo.w, c3);
            }
            float cr = (c0 + c1) + (c2 + c3);
            float d0 = (zsq + bsq[n]) - 2.0f * cr;     /* reference-style formation */
            if (d0 < best || (d0 == best && n < bidx)) { best = d0; bidx = n; }
        }
    }
    #pragma unroll
    for (int off = 32; off; off >>= 1) {
        float ob = __shfl_xor(best, off, 64);
        int   oi = __shfl_xor(bidx, off, 64);
        if (ob < best || (ob == best && oi < bidx)) { best = ob; bidx = oi; }
    }
    __shared__ float sb[4]; __shared__ int si[4];
    if (lane == 0) { sb[w] = best; si[w] = bidx; }
    __syncthreads();
    if (w != 0) return;

    best = sb[0]; bidx = si[0];
    for (int i = 1; i < 4; i++) {
        float vv = sb[i]; int ii = si[i];
        if (vv < best || (vv == best && ii < bidx)) { best = vv; bidx = ii; }
    }

    int ind = min(bidx, N_E - 1);
    int kk = 0;                              /* coe = kk * PERS */
    size_t ibase = (size_t)b * TT;
    if (lane == 0) wind[ibase] = ind;

    const float* eb = e + (size_t)b * TT * NPAD;
    const float QS = 1.0f / PERS;            /* 10240 */

    float Av[31], Bv[31];
    int   q[31];

    int cb = min(ind, 960);
    {
        #pragma unroll
        for (int j = 0; j < 31; j++) {
            const float* p = eb + (size_t)(1 + j) * NPAD + cb + lane;
            Av[j] = p[0]; Bv[j] = p[1];
        }
        bool cap = (cb + lane == 1023);
        #pragma unroll
        for (int j = 0; j < 31; j++) {
            int qv = (int)((Bv[j] - Av[j]) * QS);
            q[j] = cap ? 0 : qv;
        }
    }

    int t = 1;
    for (int c = 0; c < 33; c++) {
        int cbn = min(ind, 960);             /* base for chunk c+1 (<= +31 drift/chunk) */
        if (c < 32) {
            /* issue loads for chunk c+1 NOW; consumed only after the chain below */
            #pragma unroll
            for (int j = 0; j < 31; j++) {
                int tn = t + 31 + j; tn = tn < 1024 ? tn : 1023;
                const float* p = eb + (size_t)tn * NPAD + cbn + lane;
                Av[j] = p[0]; Bv[j] = p[1];
            }
        }
        /* fence: loads above must be emitted before the serial chain */
        __builtin_amdgcn_sched_barrier(0);

        int packed = 0;
        #pragma unroll
        for (int j = 0; j < 31; j++) {
            int rel = ind - cb;
            int qv = __builtin_amdgcn_readlane(q[j], rel);
            bool stay = (kk <= qv);
            int ip1 = ind + 1; ip1 = ip1 < 1023 ? ip1 : 1023;
            ind = stay ? ind : ip1;
            kk  = stay ? kk + 1 : 0;
            packed = (lane == j) ? ind : packed;
        }
        if (lane < 31) wind[ibase + t + lane] = packed;

        /* fence: q-compute (and its vmcnt waits) stays after the chain */
        __builtin_amdgcn_sched_barrier(0);

        if (c < 32) {
            bool cap = (cbn + lane == 1023);
            #pragma unroll
            for (int j = 0; j < 31; j++) {
                int qv = (int)((Bv[j] - Av[j]) * QS);
                q[j] = cap ? 0 : qv;
            }
        }
        cb = cbn;
        t += 31;
    }
}

/* ---------------- K3: per-row hinge-loss partial + z_q gather + idx emit ------ */
__global__ __launch_bounds__(256) void k3_loss_zq(const float* __restrict__ e,
                                                  const int* __restrict__ wind,
                                                  const float* __restrict__ book,
                                                  float* __restrict__ part,
                                                  float* __restrict__ out) {
    int rIdx = blockIdx.x, tid = threadIdx.x;
    int ind = wind[rIdx];
    const float* er = e + (size_t)rIdx * NPAD;
    float eind = er[ind];
    float p = 0.0f;
    for (int n = tid; n < NCOL; n += 256) {
        float v = eind - er[n] + EPSC;
        p += v > 0.0f ? v : 0.0f;
    }
    __shared__ float sd[256];
    sd[tid] = p; __syncthreads();
    for (int s = 128; s > 0; s >>= 1) { if (tid < s) sd[tid] += sd[tid + s]; __syncthreads(); }
    if (tid == 0) { part[rIdx] = sd[0]; out[OUT_IDX + rIdx] = (float)ind; }
    out[(size_t)rIdx * 256 + tid] = book[(size_t)ind * EDIM + tid];   /* z_q */
}

/* ---------------- K4: final loss reduce + v ---------------- */
__global__ __launch_bounds__(256) void k4_final(const float* __restrict__ part,
                                                const int* __restrict__ wind,
                                                float* __restrict__ out) {
    int tid = threadIdx.x;
    float s = 0.0f;
    for (int i = tid; i < NROW; i += 256) s += part[i];
    __shared__ float sd[256];
    sd[tid] = s; __syncthreads();
    for (int st = 128; st > 0; st >>= 1) { if (tid < st) sd[tid] += sd[tid + st]; __syncthreads(); }
    if (tid == 0) {
        int mn = wind[0], mx = wind[TT - 1];
        for (int b = 1; b < BB; b++) {
            mn = min(mn, wind[(size_t)b * TT]);
            mx = max(mx, wind[(size_t)b * TT + TT - 1]);
        }
        out[OUT_LOSS] = 1.25f * sd[0] / ((float)NROW * (float)NCOL);
        out[OUT_V] = (float)(mx - mn);
    }
}

extern "C" void kernel_launch(void* const* d_in, const int* in_sizes, int n_in,
                              void* d_out, int out_size, void* d_ws, size_t ws_size,
                              hipStream_t stream) {
    const float* z    = (const float*)d_in[0];
    const float* book = (const float*)d_in[1];
    char* ws = (char*)d_ws;
    unsigned short* zb = (unsigned short*)(ws + WS_ZB);
    unsigned short* bb = (unsigned short*)(ws + WS_BBF);
    float* bsq  = (float*)(ws + WS_BSQ);
    float* e    = (float*)(ws + WS_E);
    int*   wind = (int*)(ws + WS_IND);
    float* part = (float*)(ws + WS_PART);
    float* out  = (float*)d_out;

    hipLaunchKernelGGL(k0_prep,    dim3(4096 + 1152), dim3(256), 0, stream, z, book, zb, bb, bsq);
    hipLaunchKernelGGL(k1_gemm,    dim3(128, 9),      dim3(256), 0, stream, zb, bb, bsq, e);
    hipLaunchKernelGGL(k2_scan,    dim3(16),          dim3(256), 0, stream, z, book, bsq, e, wind);
    hipLaunchKernelGGL(k3_loss_zq, dim3(16384),       dim3(256), 0, stream, e, wind, book, part, out);
    hipLaunchKernelGGL(k4_final,   dim3(1),           dim3(256), 0, stream, part, wind, out);
}

// Round 2
// 258.690 us; speedup vs baseline: 1.0126x; 1.0126x over previous
//
#include <hip/hip_runtime.h>

#define N_E   1024
#define EDIM  256
#define BB    16
#define TT    1024
#define NROW  (BB*TT)        /* 16384 */
#define NCOL  1025
#define NPAD  1152           /* 9*128 */
#define PERS  (0.1f/1024.0f)
#define EPSC  (1e-6f/1024.0f)

/* d_out layout (float32): z_q [0,4194304) | loss 4194304 | ind [4194305,+16384) | v 4210689 */
#define OUT_LOSS 4194304
#define OUT_IDX  4194305
#define OUT_V    4210689

/* ws layout (bytes) */
#define WS_ZB   0ull                               /* 16384*256*2  = 8388608  */
#define WS_BBF  8388608ull                         /* 1152*256*2   = 589824   */
#define WS_BSQ  8978432ull                         /* 1152*4       = 4608     */
#define WS_E    8983552ull                         /* 16384*1152*4 = 75497472 */
#define WS_IND  84481024ull                        /* 16384*4                 */
#define WS_PART 84546560ull                        /* 16384*4                 */

typedef __attribute__((ext_vector_type(8))) short short8;
typedef __attribute__((ext_vector_type(4))) float floatx4;

__device__ __forceinline__ unsigned short f2bf(float f) {
    unsigned int u = __float_as_uint(f);
    u = (u + 0x7fffu + ((u >> 16) & 1u)) >> 16;   /* RNE */
    return (unsigned short)u;
}

/* async 4B/lane global->LDS: no VGPR destination, side-effecting => cannot be
   sunk past the serial chain by MachineSink (the failure mode of the
   sched_barrier-only attempt: VGPR_Count stayed 68, loads got serialized). */
__device__ __forceinline__ void gload_lds4(const float* g, float* l) {
    __builtin_amdgcn_global_load_lds(
        (const __attribute__((address_space(1))) void*)g,
        (__attribute__((address_space(3))) void*)l, 4, 0, 0);
}

/* ---------------- K0: convert z/book -> bf16, compute bsq (fp32) ---------------- */
__global__ __launch_bounds__(256) void k0_prep(const float* __restrict__ z,
                                               const float* __restrict__ book,
                                               unsigned short* __restrict__ zb,
                                               unsigned short* __restrict__ bb,
                                               float* __restrict__ bsq) {
    int bx = blockIdx.x, tid = threadIdx.x;
    if (bx < 4096) {                     /* z: 4096 blocks * 256 thr * 4 floats */
        float4 v = ((const float4*)z)[bx * 256 + tid];
        size_t o = ((size_t)bx * 256 + tid) * 4;
        zb[o + 0] = f2bf(v.x); zb[o + 1] = f2bf(v.y);
        zb[o + 2] = f2bf(v.z); zb[o + 3] = f2bf(v.w);
    } else {                             /* book rows, padded to 1152 with zeros */
        int row = bx - 4096;             /* 0..1151 */
        float v = (row < NCOL) ? book[(size_t)row * EDIM + tid] : 0.0f;
        bb[(size_t)row * EDIM + tid] = f2bf(v);
        __shared__ float sd[256];
        sd[tid] = v * v;
        __syncthreads();
        for (int s = 128; s > 0; s >>= 1) { if (tid < s) sd[tid] += sd[tid + s]; __syncthreads(); }
        if (tid == 0) bsq[row] = sd[0];
    }
}

/* ---------------- K1: e[r][n] = bsq[n] - 2 * dot(z[r], book[n])  (bf16 MFMA) ---- */
__global__ __launch_bounds__(256) void k1_gemm(const unsigned short* __restrict__ zb,
                                               const unsigned short* __restrict__ bb,
                                               const float* __restrict__ bsq,
                                               float* __restrict__ e) {
    int tid = threadIdx.x;
    int lane = tid & 63, w = tid >> 6;
    int mBase = blockIdx.x * 128 + (w >> 1) * 64;
    int nBase = blockIdx.y * 128 + (w & 1) * 64;
    int r = lane & 15, q = lane >> 4;

    floatx4 acc[4][4];
    #pragma unroll
    for (int i = 0; i < 4; i++)
        #pragma unroll
        for (int j = 0; j < 4; j++) acc[i][j] = (floatx4){0.f, 0.f, 0.f, 0.f};

    const short8* A = (const short8*)zb;   /* row stride 256 bf16 = 32 short8 */
    const short8* Bm = (const short8*)bb;

    #pragma unroll
    for (int ks = 0; ks < 8; ks++) {
        int k8 = ks * 4 + q;               /* short8 index in row: (ks*32+q*8)/8 */
        short8 a[4], b[4];
        #pragma unroll
        for (int i = 0; i < 4; i++) a[i] = A[(size_t)(mBase + i * 16 + r) * 32 + k8];
        #pragma unroll
        for (int j = 0; j < 4; j++) b[j] = Bm[(size_t)(nBase + j * 16 + r) * 32 + k8];
        #pragma unroll
        for (int i = 0; i < 4; i++)
            #pragma unroll
            for (int j = 0; j < 4; j++)
                acc[i][j] = __builtin_amdgcn_mfma_f32_16x16x32_bf16(a[i], b[j], acc[i][j], 0, 0, 0);
    }

    float bsql[4];
    #pragma unroll
    for (int j = 0; j < 4; j++) bsql[j] = bsq[nBase + j * 16 + r];

    #pragma unroll
    for (int i = 0; i < 4; i++)
        #pragma unroll
        for (int rr = 0; rr < 4; rr++) {
            int m = mBase + i * 16 + q * 4 + rr;
            float* erow = e + (size_t)m * NPAD;
            #pragma unroll
            for (int j = 0; j < 4; j++)
                erow[nBase + j * 16 + r] = fmaf(-2.0f, acc[i][j][rr], bsql[j]);
        }
}

/* ---------------- K2: serial neighbor scan, one block per batch row ------------
   Phase A (4 waves): fp32 argmin of d[b,0,:] reference-style.
   Phase B (wave 0): integer-scan formulation. stay <=> kk <= q, coe = kk*P,
   q = trunc(m/P) precomputed per (t, col) vectorized.
   PIPELINE: per chunk c, the 62 window loads for chunk c+1 are issued via
   global_load_lds (async, zero VGPR destinations, side-effecting => the
   compiler cannot sink them past the chain). The 31-step serial chain then
   runs while the loads are in flight; an explicit vmcnt(0) drains them just
   before the ds_read + q-compute. LDS is double-buffered.                   */
__global__ __launch_bounds__(256, 1) void k2_scan(const float* __restrict__ z,
                                                  const float* __restrict__ book,
                                                  const float* __restrict__ bsq,
                                                  const float* __restrict__ e,
                                                  int* __restrict__ wind) {
    __shared__ float sb[4]; __shared__ int si[4];
    __shared__ float ldsq[2][31][2][64];   /* [buf][row j][A/B][lane] = 31744 B */

    int b = blockIdx.x, tid = threadIdx.x;
    int lane = tid & 63, w = tid >> 6;

    const float4* zr = (const float4*)(z + (size_t)b * TT * EDIM);  /* t=0 row */
    float4 zv = zr[lane];
    float s = zv.x * zv.x + zv.y * zv.y + zv.z * zv.z + zv.w * zv.w;
    #pragma unroll
    for (int off = 32; off; off >>= 1) s += __shfl_xor(s, off, 64);
    float zsq = s;

    float best = 3.4e38f; int bidx = 0;
    for (int wi = w; wi < 17; wi += 4) {
        int n = wi * 64 + lane;
        if (n < NCOL) {
            const float4* br = (const float4*)(book + (size_t)n * EDIM);
            float c0 = 0.f, c1 = 0.f, c2 = 0.f, c3 = 0.f;
            #pragma unroll 8
            for (int k = 0; k < 64; k++) {
                float4 bo = br[k]; float4 za = zr[k];
                c0 = fmaf(za.x, bo.x, c0); c1 = fmaf(za.y, bo.y, c1);
                c2 = fmaf(za.z, bo.z, c2); c3 = fmaf(za.w, bo.w, c3);
            }
            float cr = (c0 + c1) + (c2 + c3);
            float d0 = (zsq + bsq[n]) - 2.0f * cr;     /* reference-style formation */
            if (d0 < best || (d0 == best && n < bidx)) { best = d0; bidx = n; }
        }
    }
    #pragma unroll
    for (int off = 32; off; off >>= 1) {
        float ob = __shfl_xor(best, off, 64);
        int   oi = __shfl_xor(bidx, off, 64);
        if (ob < best || (ob == best && oi < bidx)) { best = ob; bidx = oi; }
    }
    if (lane == 0) { sb[w] = best; si[w] = bidx; }
    __syncthreads();
    if (w != 0) return;

    best = sb[0]; bidx = si[0];
    for (int i = 1; i < 4; i++) {
        float vv = sb[i]; int ii = si[i];
        if (vv < best || (vv == best && ii < bidx)) { best = vv; bidx = ii; }
    }

    int ind = min(bidx, N_E - 1);
    int kk = 0;                              /* coe = kk * PERS */
    size_t ibase = (size_t)b * TT;
    if (lane == 0) wind[ibase] = ind;

    const float* eb = e + (size_t)b * TT * NPAD;
    const float QS = 1.0f / PERS;            /* 10240 */

    int q[31];

    int cb = min(ind, 960);
    {   /* prologue: chunk 0 (rows t=1..31) -> lds buf 0, no overlap (once) */
        #pragma unroll
        for (int j = 0; j < 31; j++) {
            const float* p = eb + (size_t)(1 + j) * NPAD + cb + lane;
            gload_lds4(p,     &ldsq[0][j][0][0]);
            gload_lds4(p + 1, &ldsq[0][j][1][0]);
        }
        asm volatile("s_waitcnt vmcnt(0)" ::: "memory");
        __builtin_amdgcn_sched_barrier(0);
        bool cap = (cb + lane == 1023);
        #pragma unroll
        for (int j = 0; j < 31; j++) {
            int qv = (int)((ldsq[0][j][1][lane] - ldsq[0][j][0][lane]) * QS);
            q[j] = cap ? 0 : qv;
        }
    }

    int t = 1;
    for (int c = 0; c < 33; c++) {
        int cbn = min(ind, 960);             /* base for chunk c+1 (<= +31 drift/chunk) */
        if (c < 32) {
            /* issue async loads for chunk c+1 NOW; drained after the chain */
            int bufn = (c + 1) & 1;
            #pragma unroll
            for (int j = 0; j < 31; j++) {
                int tn = t + 31 + j; tn = tn < 1024 ? tn : 1023;
                const float* p = eb + (size_t)tn * NPAD + cbn + lane;
                gload_lds4(p,     &ldsq[bufn][j][0][0]);
                gload_lds4(p + 1, &ldsq[bufn][j][1][0]);
            }
        }
        __builtin_amdgcn_sched_barrier(0);

        int packed = 0;
        #pragma unroll
        for (int j = 0; j < 31; j++) {
            int rel = ind - cb;
            int qv = __builtin_amdgcn_readlane(q[j], rel);
            bool stay = (kk <= qv);
            int ip1 = ind + 1; ip1 = ip1 < 1023 ? ip1 : 1023;
            ind = stay ? ind : ip1;
            kk  = stay ? kk + 1 : 0;
            packed = (lane == j) ? ind : packed;
        }
        __builtin_amdgcn_sched_barrier(0);

        if (c < 32) {
            int bufn = (c + 1) & 1;
            asm volatile("s_waitcnt vmcnt(0)" ::: "memory");
            __builtin_amdgcn_sched_barrier(0);
            bool cap = (cbn + lane == 1023);
            #pragma unroll
            for (int j = 0; j < 31; j++) {
                int qv = (int)((ldsq[bufn][j][1][lane] - ldsq[bufn][j][0][lane]) * QS);
                q[j] = cap ? 0 : qv;
            }
        }
        /* store last: keeps the vmcnt(0) above from stalling on store-acks */
        if (lane < 31) wind[ibase + t + lane] = packed;
        cb = cbn;
        t += 31;
    }
}

/* ---------------- K3: per-row hinge-loss partial + z_q gather + idx emit ------ */
__global__ __launch_bounds__(256) void k3_loss_zq(const float* __restrict__ e,
                                                  const int* __restrict__ wind,
                                                  const float* __restrict__ book,
                                                  float* __restrict__ part,
                                                  float* __restrict__ out) {
    int rIdx = blockIdx.x, tid = threadIdx.x;
    int ind = wind[rIdx];
    const float* er = e + (size_t)rIdx * NPAD;
    float eind = er[ind];
    float p = 0.0f;
    for (int n = tid; n < NCOL; n += 256) {
        float v = eind - er[n] + EPSC;
        p += v > 0.0f ? v : 0.0f;
    }
    __shared__ float sd[256];
    sd[tid] = p; __syncthreads();
    for (int s = 128; s > 0; s >>= 1) { if (tid < s) sd[tid] += sd[tid + s]; __syncthreads(); }
    if (tid == 0) { part[rIdx] = sd[0]; out[OUT_IDX + rIdx] = (float)ind; }
    out[(size_t)rIdx * 256 + tid] = book[(size_t)ind * EDIM + tid];   /* z_q */
}

/* ---------------- K4: final loss reduce + v ---------------- */
__global__ __launch_bounds__(256) void k4_final(const float* __restrict__ part,
                                                const int* __restrict__ wind,
                                                float* __restrict__ out) {
    int tid = threadIdx.x;
    float s = 0.0f;
    for (int i = tid; i < NROW; i += 256) s += part[i];
    __shared__ float sd[256];
    sd[tid] = s; __syncthreads();
    for (int st = 128; st > 0; st >>= 1) { if (tid < st) sd[tid] += sd[tid + st]; __syncthreads(); }
    if (tid == 0) {
        int mn = wind[0], mx = wind[TT - 1];
        for (int b = 1; b < BB; b++) {
            mn = min(mn, wind[(size_t)b * TT]);
            mx = max(mx, wind[(size_t)b * TT + TT - 1]);
        }
        out[OUT_LOSS] = 1.25f * sd[0] / ((float)NROW * (float)NCOL);
        out[OUT_V] = (float)(mx - mn);
    }
}

extern "C" void kernel_launch(void* const* d_in, const int* in_sizes, int n_in,
                              void* d_out, int out_size, void* d_ws, size_t ws_size,
                              hipStream_t stream) {
    const float* z    = (const float*)d_in[0];
    const float* book = (const float*)d_in[1];
    char* ws = (char*)d_ws;
    unsigned short* zb = (unsigned short*)(ws + WS_ZB);
    unsigned short* bb = (unsigned short*)(ws + WS_BBF);
    float* bsq  = (float*)(ws + WS_BSQ);
    float* e    = (float*)(ws + WS_E);
    int*   wind = (int*)(ws + WS_IND);
    float* part = (float*)(ws + WS_PART);
    float* out  = (float*)d_out;

    hipLaunchKernelGGL(k0_prep,    dim3(4096 + 1152), dim3(256), 0, stream, z, book, zb, bb, bsq);
    hipLaunchKernelGGL(k1_gemm,    dim3(128, 9),      dim3(256), 0, stream, zb, bb, bsq, e);
    hipLaunchKernelGGL(k2_scan,    dim3(16),          dim3(256), 0, stream, z, book, bsq, e, wind);
    hipLaunchKernelGGL(k3_loss_zq, dim3(16384),       dim3(256), 0, stream, e, wind, book, part, out);
    hipLaunchKernelGGL(k4_final,   dim3(1),           dim3(256), 0, stream, part, wind, out);
}

// Round 3
// 256.625 us; speedup vs baseline: 1.0207x; 1.0080x over previous
//
#include <hip/hip_runtime.h>

#define N_E   1024
#define EDIM  256
#define BB    16
#define TT    1024
#define NROW  (BB*TT)        /* 16384 */
#define NCOL  1025
#define NPAD  1152           /* 9*128 */
#define PERS  (0.1f/1024.0f)
#define EPSC  (1e-6f/1024.0f)

/* d_out layout (float32): z_q [0,4194304) | loss 4194304 | ind [4194305,+16384) | v 4210689 */
#define OUT_LOSS 4194304
#define OUT_IDX  4194305
#define OUT_V    4210689

/* ws layout (bytes) */
#define WS_ZB   0ull                               /* 16384*256*2  = 8388608  */
#define WS_BBF  8388608ull                         /* 1152*256*2   = 589824   */
#define WS_BSQ  8978432ull                         /* 1152*4       = 4608     */
#define WS_E    8983552ull                         /* 16384*1152*4 = 75497472 */
#define WS_IND  84481024ull                        /* 16384*4                 */
#define WS_PART 84546560ull                        /* 16384*4                 */

typedef __attribute__((ext_vector_type(8))) short short8;
typedef __attribute__((ext_vector_type(4))) float floatx4;

__device__ __forceinline__ unsigned short f2bf(float f) {
    unsigned int u = __float_as_uint(f);
    u = (u + 0x7fffu + ((u >> 16) & 1u)) >> 16;   /* RNE */
    return (unsigned short)u;
}

/* Early-issued plain VMEM load the compiler can NOT sink/split/remat.
   (Round-0: compiler sank plain loads to use -> serial latency, 105us.
    Round-2: global_load_lds from one wave drains ~serially -> 117us.
    Plain global_load_dword pipelines from one wave [m135]; asm volatile
    pins the issue point and forces the result to stay live.)            */
__device__ __forceinline__ float gload_f32(const float* p) {
    float r;
    asm volatile("global_load_dword %0, %1, off" : "=v"(r) : "v"(p));
    return r;
}

/* ---------------- K0: convert z/book -> bf16, compute bsq (fp32) ---------------- */
__global__ __launch_bounds__(256) void k0_prep(const float* __restrict__ z,
                                               const float* __restrict__ book,
                                               unsigned short* __restrict__ zb,
                                               unsigned short* __restrict__ bb,
                                               float* __restrict__ bsq) {
    int bx = blockIdx.x, tid = threadIdx.x;
    if (bx < 4096) {                     /* z: 4096 blocks * 256 thr * 4 floats */
        float4 v = ((const float4*)z)[bx * 256 + tid];
        size_t o = ((size_t)bx * 256 + tid) * 4;
        zb[o + 0] = f2bf(v.x); zb[o + 1] = f2bf(v.y);
        zb[o + 2] = f2bf(v.z); zb[o + 3] = f2bf(v.w);
    } else {                             /* book rows, padded to 1152 with zeros */
        int row = bx - 4096;             /* 0..1151 */
        float v = (row < NCOL) ? book[(size_t)row * EDIM + tid] : 0.0f;
        bb[(size_t)row * EDIM + tid] = f2bf(v);
        __shared__ float sd[256];
        sd[tid] = v * v;
        __syncthreads();
        for (int s = 128; s > 0; s >>= 1) { if (tid < s) sd[tid] += sd[tid + s]; __syncthreads(); }
        if (tid == 0) bsq[row] = sd[0];
    }
}

/* ---------------- K1: e[r][n] = bsq[n] - 2 * dot(z[r], book[n])  (bf16 MFMA) ---- */
__global__ __launch_bounds__(256) void k1_gemm(const unsigned short* __restrict__ zb,
                                               const unsigned short* __restrict__ bb,
                                               const float* __restrict__ bsq,
                                               float* __restrict__ e) {
    int tid = threadIdx.x;
    int lane = tid & 63, w = tid >> 6;
    int mBase = blockIdx.x * 128 + (w >> 1) * 64;
    int nBase = blockIdx.y * 128 + (w & 1) * 64;
    int r = lane & 15, q = lane >> 4;

    floatx4 acc[4][4];
    #pragma unroll
    for (int i = 0; i < 4; i++)
        #pragma unroll
        for (int j = 0; j < 4; j++) acc[i][j] = (floatx4){0.f, 0.f, 0.f, 0.f};

    const short8* A = (const short8*)zb;   /* row stride 256 bf16 = 32 short8 */
    const short8* Bm = (const short8*)bb;

    #pragma unroll
    for (int ks = 0; ks < 8; ks++) {
        int k8 = ks * 4 + q;               /* short8 index in row: (ks*32+q*8)/8 */
        short8 a[4], b[4];
        #pragma unroll
        for (int i = 0; i < 4; i++) a[i] = A[(size_t)(mBase + i * 16 + r) * 32 + k8];
        #pragma unroll
        for (int j = 0; j < 4; j++) b[j] = Bm[(size_t)(nBase + j * 16 + r) * 32 + k8];
        #pragma unroll
        for (int i = 0; i < 4; i++)
            #pragma unroll
            for (int j = 0; j < 4; j++)
                acc[i][j] = __builtin_amdgcn_mfma_f32_16x16x32_bf16(a[i], b[j], acc[i][j], 0, 0, 0);
    }

    float bsql[4];
    #pragma unroll
    for (int j = 0; j < 4; j++) bsql[j] = bsq[nBase + j * 16 + r];

    #pragma unroll
    for (int i = 0; i < 4; i++)
        #pragma unroll
        for (int rr = 0; rr < 4; rr++) {
            int m = mBase + i * 16 + q * 4 + rr;
            float* erow = e + (size_t)m * NPAD;
            #pragma unroll
            for (int j = 0; j < 4; j++)
                erow[nBase + j * 16 + r] = fmaf(-2.0f, acc[i][j][rr], bsql[j]);
        }
}

/* ---------------- K2: serial neighbor scan, one block per batch row ------------
   Phase A (4 waves): fp32 argmin of d[b,0,:] reference-style.
   Phase B (wave 0): integer-scan. stay <=> kk <= q, q = trunc((e[col+1]-e[col])*QS)
   per (row, col) vectorized across lanes (col = cb + lane).
   PIPELINE per chunk c (branchless body, single scheduling region):
     [31 asm-volatile global_load_dword: A-window for chunk c+1]
     sched_barrier | [31-step serial chain on q[] of chunk c] | store wind
     sched_barrier | s_waitcnt vmcnt(0) | sched_barrier
     [q-compute: B = shfl_down(A,1); q = cap ? 0 : trunc((B-A)*QS)]
   B-from-shfl is exact: rel==63 only happens at col 1023 (cb==960) which is
   the cap lane (q forced 0), so lane 63's shuffle garbage is never consumed. */
__global__ __launch_bounds__(256, 1) void k2_scan(const float* __restrict__ z,
                                                  const float* __restrict__ book,
                                                  const float* __restrict__ bsq,
                                                  const float* __restrict__ e,
                                                  int* __restrict__ wind) {
    __shared__ float sb[4]; __shared__ int si[4];

    int b = blockIdx.x, tid = threadIdx.x;
    int lane = tid & 63, w = tid >> 6;

    const float4* zr = (const float4*)(z + (size_t)b * TT * EDIM);  /* t=0 row */
    float4 zv = zr[lane];
    float s = zv.x * zv.x + zv.y * zv.y + zv.z * zv.z + zv.w * zv.w;
    #pragma unroll
    for (int off = 32; off; off >>= 1) s += __shfl_xor(s, off, 64);
    float zsq = s;

    float best = 3.4e38f; int bidx = 0;
    for (int wi = w; wi < 17; wi += 4) {
        int n = wi * 64 + lane;
        if (n < NCOL) {
            const float4* br = (const float4*)(book + (size_t)n * EDIM);
            float c0 = 0.f, c1 = 0.f, c2 = 0.f, c3 = 0.f;
            #pragma unroll 8
            for (int k = 0; k < 64; k++) {
                float4 bo = br[k]; float4 za = zr[k];
                c0 = fmaf(za.x, bo.x, c0); c1 = fmaf(za.y, bo.y, c1);
                c2 = fmaf(za.z, bo.z, c2); c3 = fmaf(za.w, bo.w, c3);
            }
            float cr = (c0 + c1) + (c2 + c3);
            float d0 = (zsq + bsq[n]) - 2.0f * cr;     /* reference-style formation */
            if (d0 < best || (d0 == best && n < bidx)) { best = d0; bidx = n; }
        }
    }
    #pragma unroll
    for (int off = 32; off; off >>= 1) {
        float ob = __shfl_xor(best, off, 64);
        int   oi = __shfl_xor(bidx, off, 64);
        if (ob < best || (ob == best && oi < bidx)) { best = ob; bidx = oi; }
    }
    if (lane == 0) { sb[w] = best; si[w] = bidx; }
    __syncthreads();
    if (w != 0) return;

    best = sb[0]; bidx = si[0];
    for (int i = 1; i < 4; i++) {
        float vv = sb[i]; int ii = si[i];
        if (vv < best || (vv == best && ii < bidx)) { best = vv; bidx = ii; }
    }

    int ind = min(bidx, N_E - 1);
    int kk = 0;                              /* coe = kk * PERS */
    size_t ibase = (size_t)b * TT;
    if (lane == 0) wind[ibase] = ind;

    const float* eb = e + (size_t)b * TT * NPAD;
    const float QS = 1.0f / PERS;            /* 10240 */

    float a[31];
    int   q[31];

    int cb = min(ind, 960);
    {   /* prologue: chunk 0 (rows t=1..31) */
        #pragma unroll
        for (int j = 0; j < 31; j++)
            a[j] = gload_f32(eb + (size_t)(1 + j) * NPAD + cb + lane);
        asm volatile("s_waitcnt vmcnt(0)" ::: "memory");
        __builtin_amdgcn_sched_barrier(0);
        bool cap = (cb + lane == 1023);
        #pragma unroll
        for (int j = 0; j < 31; j++) {
            float bv = __shfl_down(a[j], 1, 64);
            int qv = (int)((bv - a[j]) * QS);
            q[j] = cap ? 0 : qv;
        }
    }

    int t = 1;
    #pragma unroll 1
    for (int c = 0; c < 33; c++) {
        int cbn = min(ind, 960);             /* window base for chunk c+1 */
        /* issue loads for chunk c+1 unconditionally (c==32: clamped dummies) */
        #pragma unroll
        for (int j = 0; j < 31; j++) {
            int tn = t + 31 + j; tn = tn < 1024 ? tn : 1023;
            a[j] = gload_f32(eb + (size_t)tn * NPAD + cbn + lane);
        }
        __builtin_amdgcn_sched_barrier(0);

        int packed = 0;
        #pragma unroll
        for (int j = 0; j < 31; j++) {
            int rel = ind - cb;
            int qv = __builtin_amdgcn_readlane(q[j], rel);
            bool stay = (kk <= qv);
            int ip1 = ind + 1; ip1 = ip1 < 1023 ? ip1 : 1023;
            ind = stay ? ind : ip1;
            kk  = stay ? kk + 1 : 0;
            packed = (lane == j) ? ind : packed;
        }
        if (lane < 31) wind[ibase + t + lane] = packed;
        __builtin_amdgcn_sched_barrier(0);

        asm volatile("s_waitcnt vmcnt(0)" ::: "memory");
        __builtin_amdgcn_sched_barrier(0);
        bool cap = (cbn + lane == 1023);
        #pragma unroll
        for (int j = 0; j < 31; j++) {
            float bv = __shfl_down(a[j], 1, 64);
            int qv = (int)((bv - a[j]) * QS);
            q[j] = cap ? 0 : qv;
        }
        cb = cbn;
        t += 31;
    }
}

/* ---------------- K3: per-row hinge-loss partial + z_q gather + idx emit ------ */
__global__ __launch_bounds__(256) void k3_loss_zq(const float* __restrict__ e,
                                                  const int* __restrict__ wind,
                                                  const float* __restrict__ book,
                                                  float* __restrict__ part,
                                                  float* __restrict__ out) {
    int rIdx = blockIdx.x, tid = threadIdx.x;
    int ind = wind[rIdx];
    const float* er = e + (size_t)rIdx * NPAD;
    float eind = er[ind];
    float p = 0.0f;
    for (int n = tid; n < NCOL; n += 256) {
        float v = eind - er[n] + EPSC;
        p += v > 0.0f ? v : 0.0f;
    }
    __shared__ float sd[256];
    sd[tid] = p; __syncthreads();
    for (int s = 128; s > 0; s >>= 1) { if (tid < s) sd[tid] += sd[tid + s]; __syncthreads(); }
    if (tid == 0) { part[rIdx] = sd[0]; out[OUT_IDX + rIdx] = (float)ind; }
    out[(size_t)rIdx * 256 + tid] = book[(size_t)ind * EDIM + tid];   /* z_q */
}

/* ---------------- K4: final loss reduce + v ---------------- */
__global__ __launch_bounds__(256) void k4_final(const float* __restrict__ part,
                                                const int* __restrict__ wind,
                                                float* __restrict__ out) {
    int tid = threadIdx.x;
    float s = 0.0f;
    for (int i = tid; i < NROW; i += 256) s += part[i];
    __shared__ float sd[256];
    sd[tid] = s; __syncthreads();
    for (int st = 128; st > 0; st >>= 1) { if (tid < st) sd[tid] += sd[tid + st]; __syncthreads(); }
    if (tid == 0) {
        int mn = wind[0], mx = wind[TT - 1];
        for (int b = 1; b < BB; b++) {
            mn = min(mn, wind[(size_t)b * TT]);
            mx = max(mx, wind[(size_t)b * TT + TT - 1]);
        }
        out[OUT_LOSS] = 1.25f * sd[0] / ((float)NROW * (float)NCOL);
        out[OUT_V] = (float)(mx - mn);
    }
}

extern "C" void kernel_launch(void* const* d_in, const int* in_sizes, int n_in,
                              void* d_out, int out_size, void* d_ws, size_t ws_size,
                              hipStream_t stream) {
    const float* z    = (const float*)d_in[0];
    const float* book = (const float*)d_in[1];
    char* ws = (char*)d_ws;
    unsigned short* zb = (unsigned short*)(ws + WS_ZB);
    unsigned short* bb = (unsigned short*)(ws + WS_BBF);
    float* bsq  = (float*)(ws + WS_BSQ);
    float* e    = (float*)(ws + WS_E);
    int*   wind = (int*)(ws + WS_IND);
    float* part = (float*)(ws + WS_PART);
    float* out  = (float*)d_out;

    hipLaunchKernelGGL(k0_prep,    dim3(4096 + 1152), dim3(256), 0, stream, z, book, zb, bb, bsq);
    hipLaunchKernelGGL(k1_gemm,    dim3(128, 9),      dim3(256), 0, stream, zb, bb, bsq, e);
    hipLaunchKernelGGL(k2_scan,    dim3(16),          dim3(256), 0, stream, z, book, bsq, e, wind);
    hipLaunchKernelGGL(k3_loss_zq, dim3(16384),       dim3(256), 0, stream, e, wind, book, part, out);
    hipLaunchKernelGGL(k4_final,   dim3(1),           dim3(256), 0, stream, part, wind, out);
}

// Round 4
// 251.402 us; speedup vs baseline: 1.0419x; 1.0208x over previous
//
#include <hip/hip_runtime.h>

#define N_E   1024
#define EDIM  256
#define BB    16
#define TT    1024
#define NROW  (BB*TT)        /* 16384 */
#define NCOL  1025
#define NPAD  1152           /* 9*128 */
#define PERS  (0.1f/1024.0f)
#define EPSC  (1e-6f/1024.0f)

/* d_out layout (float32): z_q [0,4194304) | loss 4194304 | ind [4194305,+16384) | v 4210689 */
#define OUT_LOSS 4194304
#define OUT_IDX  4194305
#define OUT_V    4210689

/* ws layout (bytes) */
#define WS_ZB   0ull                               /* 16384*256*2  = 8388608  */
#define WS_BBF  8388608ull                         /* 1152*256*2   = 589824   */
#define WS_BSQ  8978432ull                         /* 1152*4       = 4608     */
#define WS_E    8983552ull                         /* 16384*1152*4 = 75497472 */
#define WS_IND  84481024ull                        /* 16384*4                 */
#define WS_PART 84546560ull                        /* 16384*4                 */

typedef __attribute__((ext_vector_type(8))) short short8;
typedef __attribute__((ext_vector_type(4))) float floatx4;

__device__ __forceinline__ unsigned short f2bf(float f) {
    unsigned int u = __float_as_uint(f);
    u = (u + 0x7fffu + ((u >> 16) & 1u)) >> 16;   /* RNE */
    return (unsigned short)u;
}

/* Early-issued plain VMEM load; asm volatile pins issue order. Round-3 showed
   the RESULTS must live in named scalars (VGPR_Count=36 proved float a[31]
   was lowered to scratch, whose spill-stores re-serialized every load). */
__device__ __forceinline__ float gload_f32(const float* p) {
    float r;
    asm volatile("global_load_dword %0, %1, off" : "=v"(r) : "v"(p));
    return r;
}

/* ---------------- K0: convert z/book -> bf16, compute bsq (fp32) ---------------- */
__global__ __launch_bounds__(256) void k0_prep(const float* __restrict__ z,
                                               const float* __restrict__ book,
                                               unsigned short* __restrict__ zb,
                                               unsigned short* __restrict__ bb,
                                               float* __restrict__ bsq) {
    int bx = blockIdx.x, tid = threadIdx.x;
    if (bx < 4096) {                     /* z: 4096 blocks * 256 thr * 4 floats */
        float4 v = ((const float4*)z)[bx * 256 + tid];
        size_t o = ((size_t)bx * 256 + tid) * 4;
        zb[o + 0] = f2bf(v.x); zb[o + 1] = f2bf(v.y);
        zb[o + 2] = f2bf(v.z); zb[o + 3] = f2bf(v.w);
    } else {                             /* book rows, padded to 1152 with zeros */
        int row = bx - 4096;             /* 0..1151 */
        float v = (row < NCOL) ? book[(size_t)row * EDIM + tid] : 0.0f;
        bb[(size_t)row * EDIM + tid] = f2bf(v);
        __shared__ float sd[256];
        sd[tid] = v * v;
        __syncthreads();
        for (int s = 128; s > 0; s >>= 1) { if (tid < s) sd[tid] += sd[tid + s]; __syncthreads(); }
        if (tid == 0) bsq[row] = sd[0];
    }
}

/* ---------------- K1: e[r][n] = bsq[n] - 2 * dot(z[r], book[n])  (bf16 MFMA) ---- */
__global__ __launch_bounds__(256) void k1_gemm(const unsigned short* __restrict__ zb,
                                               const unsigned short* __restrict__ bb,
                                               const float* __restrict__ bsq,
                                               float* __restrict__ e) {
    int tid = threadIdx.x;
    int lane = tid & 63, w = tid >> 6;
    int mBase = blockIdx.x * 128 + (w >> 1) * 64;
    int nBase = blockIdx.y * 128 + (w & 1) * 64;
    int r = lane & 15, q = lane >> 4;

    floatx4 acc[4][4];
    #pragma unroll
    for (int i = 0; i < 4; i++)
        #pragma unroll
        for (int j = 0; j < 4; j++) acc[i][j] = (floatx4){0.f, 0.f, 0.f, 0.f};

    const short8* A = (const short8*)zb;   /* row stride 256 bf16 = 32 short8 */
    const short8* Bm = (const short8*)bb;

    #pragma unroll
    for (int ks = 0; ks < 8; ks++) {
        int k8 = ks * 4 + q;               /* short8 index in row: (ks*32+q*8)/8 */
        short8 a[4], b[4];
        #pragma unroll
        for (int i = 0; i < 4; i++) a[i] = A[(size_t)(mBase + i * 16 + r) * 32 + k8];
        #pragma unroll
        for (int j = 0; j < 4; j++) b[j] = Bm[(size_t)(nBase + j * 16 + r) * 32 + k8];
        #pragma unroll
        for (int i = 0; i < 4; i++)
            #pragma unroll
            for (int j = 0; j < 4; j++)
                acc[i][j] = __builtin_amdgcn_mfma_f32_16x16x32_bf16(a[i], b[j], acc[i][j], 0, 0, 0);
    }

    float bsql[4];
    #pragma unroll
    for (int j = 0; j < 4; j++) bsql[j] = bsq[nBase + j * 16 + r];

    #pragma unroll
    for (int i = 0; i < 4; i++)
        #pragma unroll
        for (int rr = 0; rr < 4; rr++) {
            int m = mBase + i * 16 + q * 4 + rr;
            float* erow = e + (size_t)m * NPAD;
            #pragma unroll
            for (int j = 0; j < 4; j++)
                erow[nBase + j * 16 + r] = fmaf(-2.0f, acc[i][j][rr], bsql[j]);
        }
}

/* ---------------- K2: serial neighbor scan, one block per batch row ------------
   Phase A (4 waves): fp32 argmin of d[b,0,:] reference-style.
   Phase B (wave 0): integer-scan, depth-3 software pipeline, 15-row chunks.
   Per iteration c: [issue 15 loads, chunk c+3] [15-step chain, chunk c]
   [store] [s_waitcnt vmcnt(31): oldest chunk done] [q-compute chunk c+1].
   All window values live in NAMED scalar registers (A{0,1,2}_{0..14}, q_*):
   arrays were lowered to scratch (r3: VGPR=36), whose spill-store waits
   re-serialized every load. Drift bound: cb snapshot <= 3 chunks early ->
   rel <= 59 (<62 needed for shfl-B); cb=960 clamp caps rel at 63 = cap lane. */

#define R15(X) X(0) X(1) X(2) X(3) X(4) X(5) X(6) X(7) X(8) X(9) X(10) X(11) X(12) X(13) X(14)

#define DECLA(i) float A0_##i, A1_##i, A2_##i; int q_##i;

#define LDR(S,i) { int _t = _tb + i; _t = _t < 1024 ? _t : 1023; \
                   A##S##_##i = gload_f32(_pe + (size_t)_t * NPAD); }
#define LD0(i) LDR(0,i)
#define LD1(i) LDR(1,i)
#define LD2(i) LDR(2,i)

#define QC(S,i) { float _bv = __shfl_down(A##S##_##i, 1, 64); \
                  int _qv = (int)((_bv - A##S##_##i) * QS); \
                  q_##i = _capn ? 0 : _qv; }
#define QC0(i) QC(0,i)
#define QC1(i) QC(1,i)
#define QC2(i) QC(2,i)

#define CH(i) { int _rel = ind - cb0; \
                int _qv = __builtin_amdgcn_readlane(q_##i, _rel); \
                bool _stay = (kk <= _qv); \
                int _ip1 = ind + 1; _ip1 = _ip1 < 1023 ? _ip1 : 1023; \
                ind = _stay ? ind : _ip1; \
                kk  = _stay ? kk + 1 : 0; \
                packed = (lane == i) ? ind : packed; }

#define ITER(SI, SC) { \
    int cbI = ind < 960 ? ind : 960; \
    { const float* _pe = eb + cbI + lane; int _tb = t + 45; R15(LD##SI) } \
    __builtin_amdgcn_sched_barrier(0); \
    int packed = 0; \
    R15(CH) \
    if (lane < 15 && t + lane < 1024) wind[ibase + t + lane] = packed; \
    __builtin_amdgcn_sched_barrier(0); \
    asm volatile("s_waitcnt vmcnt(31)" ::: "memory"); \
    __builtin_amdgcn_sched_barrier(0); \
    { bool _capn = (cb1 + lane == 1023); R15(QC##SC) } \
    cb0 = cb1; cb1 = cb2; cb2 = cbI; \
    t += 15; }

__global__ __launch_bounds__(256, 1) void k2_scan(const float* __restrict__ z,
                                                  const float* __restrict__ book,
                                                  const float* __restrict__ bsq,
                                                  const float* __restrict__ e,
                                                  int* __restrict__ wind) {
    __shared__ float sb[4]; __shared__ int si[4];

    int b = blockIdx.x, tid = threadIdx.x;
    int lane = tid & 63, w = tid >> 6;

    const float4* zr = (const float4*)(z + (size_t)b * TT * EDIM);  /* t=0 row */
    float4 zv = zr[lane];
    float s = zv.x * zv.x + zv.y * zv.y + zv.z * zv.z + zv.w * zv.w;
    #pragma unroll
    for (int off = 32; off; off >>= 1) s += __shfl_xor(s, off, 64);
    float zsq = s;

    float best = 3.4e38f; int bidx = 0;
    for (int wi = w; wi < 17; wi += 4) {
        int n = wi * 64 + lane;
        if (n < NCOL) {
            const float4* br = (const float4*)(book + (size_t)n * EDIM);
            float c0 = 0.f, c1 = 0.f, c2 = 0.f, c3 = 0.f;
            #pragma unroll 8
            for (int k = 0; k < 64; k++) {
                float4 bo = br[k]; float4 za = zr[k];
                c0 = fmaf(za.x, bo.x, c0); c1 = fmaf(za.y, bo.y, c1);
                c2 = fmaf(za.z, bo.z, c2); c3 = fmaf(za.w, bo.w, c3);
            }
            float cr = (c0 + c1) + (c2 + c3);
            float d0 = (zsq + bsq[n]) - 2.0f * cr;     /* reference-style formation */
            if (d0 < best || (d0 == best && n < bidx)) { best = d0; bidx = n; }
        }
    }
    #pragma unroll
    for (int off = 32; off; off >>= 1) {
        float ob = __shfl_xor(best, off, 64);
        int   oi = __shfl_xor(bidx, off, 64);
        if (ob < best || (ob == best && oi < bidx)) { best = ob; bidx = oi; }
    }
    if (lane == 0) { sb[w] = best; si[w] = bidx; }
    __syncthreads();
    if (w != 0) return;

    best = sb[0]; bidx = si[0];
    for (int i = 1; i < 4; i++) {
        float vv = sb[i]; int ii = si[i];
        if (vv < best || (vv == best && ii < bidx)) { best = vv; bidx = ii; }
    }

    int ind = min(bidx, N_E - 1);
    int kk = 0;                              /* coe = kk * PERS */
    size_t ibase = (size_t)b * TT;
    if (lane == 0) wind[ibase] = ind;

    const float* eb = e + (size_t)b * TT * NPAD;
    const float QS = 1.0f / PERS;            /* 10240 */

    R15(DECLA)                               /* A0_*, A1_*, A2_*, q_* named regs */

    int cb0 = ind < 960 ? ind : 960;
    int cb1 = cb0, cb2 = cb0;
    /* prologue: issue chunks 0,1,2 (rows t=1..15, 16..30, 31..45) */
    { const float* _pe = eb + cb0 + lane; int _tb = 1;  R15(LD0) }
    { const float* _pe = eb + cb1 + lane; int _tb = 16; R15(LD1) }
    { const float* _pe = eb + cb2 + lane; int _tb = 31; R15(LD2) }
    asm volatile("s_waitcnt vmcnt(30)" ::: "memory");   /* chunk 0 done */
    __builtin_amdgcn_sched_barrier(0);
    { bool _capn = (cb0 + lane == 1023); R15(QC0) }     /* q for chunk 0 */

    int t = 1;
    #pragma unroll 1
    for (int cc = 0; cc < 23; cc++) {        /* 23 x 3 = 69 chunks = rows 1..1035 */
        ITER(0, 1)
        ITER(1, 2)
        ITER(2, 0)
    }
}

/* ---------------- K3: per-row hinge-loss partial + z_q gather + idx emit ------ */
__global__ __launch_bounds__(256) void k3_loss_zq(const float* __restrict__ e,
                                                  const int* __restrict__ wind,
                                                  const float* __restrict__ book,
                                                  float* __restrict__ part,
                                                  float* __restrict__ out) {
    int rIdx = blockIdx.x, tid = threadIdx.x;
    int ind = wind[rIdx];
    const float* er = e + (size_t)rIdx * NPAD;
    float eind = er[ind];
    float p = 0.0f;
    for (int n = tid; n < NCOL; n += 256) {
        float v = eind - er[n] + EPSC;
        p += v > 0.0f ? v : 0.0f;
    }
    __shared__ float sd[256];
    sd[tid] = p; __syncthreads();
    for (int s = 128; s > 0; s >>= 1) { if (tid < s) sd[tid] += sd[tid + s]; __syncthreads(); }
    if (tid == 0) { part[rIdx] = sd[0]; out[OUT_IDX + rIdx] = (float)ind; }
    out[(size_t)rIdx * 256 + tid] = book[(size_t)ind * EDIM + tid];   /* z_q */
}

/* ---------------- K4: final loss reduce + v ---------------- */
__global__ __launch_bounds__(256) void k4_final(const float* __restrict__ part,
                                                const int* __restrict__ wind,
                                                float* __restrict__ out) {
    int tid = threadIdx.x;
    float s = 0.0f;
    for (int i = tid; i < NROW; i += 256) s += part[i];
    __shared__ float sd[256];
    sd[tid] = s; __syncthreads();
    for (int st = 128; st > 0; st >>= 1) { if (tid < st) sd[tid] += sd[tid + st]; __syncthreads(); }
    if (tid == 0) {
        int mn = wind[0], mx = wind[TT - 1];
        for (int b = 1; b < BB; b++) {
            mn = min(mn, wind[(size_t)b * TT]);
            mx = max(mx, wind[(size_t)b * TT + TT - 1]);
        }
        out[OUT_LOSS] = 1.25f * sd[0] / ((float)NROW * (float)NCOL);
        out[OUT_V] = (float)(mx - mn);
    }
}

extern "C" void kernel_launch(void* const* d_in, const int* in_sizes, int n_in,
                              void* d_out, int out_size, void* d_ws, size_t ws_size,
                              hipStream_t stream) {
    const float* z    = (const float*)d_in[0];
    const float* book = (const float*)d_in[1];
    char* ws = (char*)d_ws;
    unsigned short* zb = (unsigned short*)(ws + WS_ZB);
    unsigned short* bb = (unsigned short*)(ws + WS_BBF);
    float* bsq  = (float*)(ws + WS_BSQ);
    float* e    = (float*)(ws + WS_E);
    int*   wind = (int*)(ws + WS_IND);
    float* part = (float*)(ws + WS_PART);
    float* out  = (float*)d_out;

    hipLaunchKernelGGL(k0_prep,    dim3(4096 + 1152), dim3(256), 0, stream, z, book, zb, bb, bsq);
    hipLaunchKernelGGL(k1_gemm,    dim3(128, 9),      dim3(256), 0, stream, zb, bb, bsq, e);
    hipLaunchKernelGGL(k2_scan,    dim3(16),          dim3(256), 0, stream, z, book, bsq, e, wind);
    hipLaunchKernelGGL(k3_loss_zq, dim3(16384),       dim3(256), 0, stream, e, wind, book, part, out);
    hipLaunchKernelGGL(k4_final,   dim3(1),           dim3(256), 0, stream, part, wind, out);
}

// Round 6
// 240.986 us; speedup vs baseline: 1.0869x; 1.0432x over previous
//
#include <hip/hip_runtime.h>

#define N_E   1024
#define EDIM  256
#define BB    16
#define TT    1024
#define NROW  (BB*TT)        /* 16384 */
#define NCOL  1025
#define NPAD  1152           /* 9*128 */
#define PERS  (0.1f/1024.0f)
#define EPSC  (1e-6f/1024.0f)

/* d_out layout (float32): z_q [0,4194304) | loss 4194304 | ind [4194305,+16384) | v 4210689 */
#define OUT_LOSS 4194304
#define OUT_IDX  4194305
#define OUT_V    4210689

/* ws layout (bytes) */
#define WS_ZB   0ull                               /* 16384*256*2  = 8388608  */
#define WS_BBF  8388608ull                         /* 1152*256*2   = 589824   */
#define WS_BSQ  8978432ull                         /* 1152*4       = 4608     */
#define WS_E    8983552ull                         /* 16384*1152*4 = 75497472 */
#define WS_IND  84481024ull                        /* 16384*4                 */
#define WS_PART 84546560ull                        /* 16384*4                 */

typedef __attribute__((ext_vector_type(8))) short short8;
typedef __attribute__((ext_vector_type(4))) float floatx4;

__device__ __forceinline__ unsigned short f2bf(float f) {
    unsigned int u = __float_as_uint(f);
    u = (u + 0x7fffu + ((u >> 16) & 1u)) >> 16;   /* RNE */
    return (unsigned short)u;
}

/* Early-issued plain VMEM load; asm volatile pins issue order and result
   liveness. Rounds 0-4 showed any prefetch needing >~45 live VGPRs gets
   spilled to scratch (spill-store waits re-serialize every load). The fix
   is structural: the new 32-col window needs only ~15 live registers. */
__device__ __forceinline__ float gload_f32(const float* p) {
    float r;
    asm volatile("global_load_dword %0, %1, off" : "=v"(r) : "v"(p));
    return r;
}

/* ---------------- K0: convert z/book -> bf16, compute bsq (fp32) ---------------- */
__global__ __launch_bounds__(256) void k0_prep(const float* __restrict__ z,
                                               const float* __restrict__ book,
                                               unsigned short* __restrict__ zb,
                                               unsigned short* __restrict__ bb,
                                               float* __restrict__ bsq) {
    int bx = blockIdx.x, tid = threadIdx.x;
    if (bx < 4096) {                     /* z: 4096 blocks * 256 thr * 4 floats */
        float4 v = ((const float4*)z)[bx * 256 + tid];
        size_t o = ((size_t)bx * 256 + tid) * 4;
        zb[o + 0] = f2bf(v.x); zb[o + 1] = f2bf(v.y);
        zb[o + 2] = f2bf(v.z); zb[o + 3] = f2bf(v.w);
    } else {                             /* book rows, padded to 1152 with zeros */
        int row = bx - 4096;             /* 0..1151 */
        float v = (row < NCOL) ? book[(size_t)row * EDIM + tid] : 0.0f;
        bb[(size_t)row * EDIM + tid] = f2bf(v);
        __shared__ float sd[256];
        sd[tid] = v * v;
        __syncthreads();
        for (int s = 128; s > 0; s >>= 1) { if (tid < s) sd[tid] += sd[tid + s]; __syncthreads(); }
        if (tid == 0) bsq[row] = sd[0];
    }
}

/* ---------------- K1: e[r][n] = bsq[n] - 2 * dot(z[r], book[n])  (bf16 MFMA) ---- */
__global__ __launch_bounds__(256) void k1_gemm(const unsigned short* __restrict__ zb,
                                               const unsigned short* __restrict__ bb,
                                               const float* __restrict__ bsq,
                                               float* __restrict__ e) {
    int tid = threadIdx.x;
    int lane = tid & 63, w = tid >> 6;
    int mBase = blockIdx.x * 128 + (w >> 1) * 64;
    int nBase = blockIdx.y * 128 + (w & 1) * 64;
    int r = lane & 15, q = lane >> 4;

    floatx4 acc[4][4];
    #pragma unroll
    for (int i = 0; i < 4; i++)
        #pragma unroll
        for (int j = 0; j < 4; j++) acc[i][j] = (floatx4){0.f, 0.f, 0.f, 0.f};

    const short8* A = (const short8*)zb;   /* row stride 256 bf16 = 32 short8 */
    const short8* Bm = (const short8*)bb;

    #pragma unroll
    for (int ks = 0; ks < 8; ks++) {
        int k8 = ks * 4 + q;               /* short8 index in row: (ks*32+q*8)/8 */
        short8 a[4], b[4];
        #pragma unroll
        for (int i = 0; i < 4; i++) a[i] = A[(size_t)(mBase + i * 16 + r) * 32 + k8];
        #pragma unroll
        for (int j = 0; j < 4; j++) b[j] = Bm[(size_t)(nBase + j * 16 + r) * 32 + k8];
        #pragma unroll
        for (int i = 0; i < 4; i++)
            #pragma unroll
            for (int j = 0; j < 4; j++)
                acc[i][j] = __builtin_amdgcn_mfma_f32_16x16x32_bf16(a[i], b[j], acc[i][j], 0, 0, 0);
    }

    float bsql[4];
    #pragma unroll
    for (int j = 0; j < 4; j++) bsql[j] = bsq[nBase + j * 16 + r];

    #pragma unroll
    for (int i = 0; i < 4; i++)
        #pragma unroll
        for (int rr = 0; rr < 4; rr++) {
            int m = mBase + i * 16 + q * 4 + rr;
            float* erow = e + (size_t)m * NPAD;
            #pragma unroll
            for (int j = 0; j < 4; j++)
                erow[nBase + j * 16 + r] = fmaf(-2.0f, acc[i][j][rr], bsql[j]);
        }
}

/* ---------------- K2: serial neighbor scan, one block per batch row ------------
   Phase A (4 waves): fp32 argmin of d[b,0,:] reference-style.
   Phase B (wave 0): integer-scan. 32-col window, 2 rows packed per 64-lane
   load (lane = (row&1)*32 + col). Chunk = 10 rows -> 5 loads/chunk, depth-2
   pipeline -> only ~15 live prefetch VGPRs (register-spill-proof; rounds 0-4
   all died to the allocator spilling >45 live prefetch regs).
   Drift bound: base snapshot at iter c serves chunk c+2; drift <= 10+10+9=29
   <= 30 usable cols. Base clamp min(ind,992) puts col 1023 on the cap lane
   (q forced 0 there = exact reference behavior at ind=1023); shfl_down width
   32 keeps the col+1 neighbor inside the row segment.
   vmcnt ledger (steady state): queue at the wait = [c+1 loads x5, store,
   c+2 loads x5, store] = 12 -> vmcnt(6) retires exactly chunk c+1's loads
   + the older store. Prologue: [init store, chunk0 x5, chunk1 x5] = 11 ->
   vmcnt(5) retires store + chunk0.                                           */

#define DECLW float A0_0, A0_1, A0_2, A0_3, A0_4, A1_0, A1_1, A1_2, A1_3, A1_4; \
              int q_0, q_1, q_2, q_3, q_4;

#define LDOP(S,k) { int _t = _tb + 2*k + _g; _t = _t < 1024 ? _t : 1023; \
                    A##S##_##k = gload_f32(_pe + (size_t)_t * NPAD); }
#define LDSET(S) LDOP(S,0) LDOP(S,1) LDOP(S,2) LDOP(S,3) LDOP(S,4)

#define QCOP(S,k) { float _bv = __shfl_down(A##S##_##k, 1, 32); \
                    int _qv = (int)((_bv - A##S##_##k) * QS); \
                    q_##k = _capn ? 0 : _qv; }
#define QCSET(S) QCOP(S,0) QCOP(S,1) QCOP(S,2) QCOP(S,3) QCOP(S,4)

/* chain step: row j of chunk, q register k=j>>1, half h=(j&1)*32 */
#define CHS(j,k,h) { int _rel = ind - cbc; \
                     int _qv = __builtin_amdgcn_readlane(q_##k, _rel + h); \
                     bool _stay = (kk <= _qv); \
                     int _ip1 = ind + 1; _ip1 = _ip1 < 1023 ? _ip1 : 1023; \
                     ind = _stay ? ind : _ip1; \
                     kk  = _stay ? kk + 1 : 0; \
                     packed = (lane == j) ? ind : packed; }
#define CHAIN CHS(0,0,0) CHS(1,0,32) CHS(2,1,0) CHS(3,1,32) CHS(4,2,0) \
              CHS(5,2,32) CHS(6,3,0) CHS(7,3,32) CHS(8,4,0) CHS(9,4,32)

/* one pipeline iteration: chunk c (A-set SI holds chunk c's data already
   consumed into q; its registers are reused to prefetch chunk c+2).
   SQ = (c+1)&1: q-compute for chunk c+1 after the counted wait. */
#define ITERX(SI, SQ) { \
    int cbI = ind < 992 ? ind : 992;                 /* base, chunk c+2 */ \
    { const float* _pe = eb + cbI + _cl; int _tb = t + 20; LDSET(SI) } \
    __builtin_amdgcn_sched_barrier(0); \
    int packed = 0; \
    CHAIN \
    if (lane < 10 && t + lane < 1024) wind[ibase + t + lane] = packed; \
    __builtin_amdgcn_sched_barrier(0); \
    asm volatile("s_waitcnt vmcnt(6)" ::: "memory"); /* chunk c+1 loads done */ \
    __builtin_amdgcn_sched_barrier(0); \
    { bool _capn = (cbn + _cl == 1023); QCSET(SQ) } \
    cbc = cbn; cbn = cbI; \
    t += 10; }

__global__ __launch_bounds__(256, 1) void k2_scan(const float* __restrict__ z,
                                                  const float* __restrict__ book,
                                                  const float* __restrict__ bsq,
                                                  const float* __restrict__ e,
                                                  int* __restrict__ wind) {
    __shared__ float sb[4]; __shared__ int si[4];

    int b = blockIdx.x, tid = threadIdx.x;
    int lane = tid & 63, w = tid >> 6;

    const float4* zr = (const float4*)(z + (size_t)b * TT * EDIM);  /* t=0 row */
    float4 zv = zr[lane];
    float s = zv.x * zv.x + zv.y * zv.y + zv.z * zv.z + zv.w * zv.w;
    #pragma unroll
    for (int off = 32; off; off >>= 1) s += __shfl_xor(s, off, 64);
    float zsq = s;

    float best = 3.4e38f; int bidx = 0;
    for (int wi = w; wi < 17; wi += 4) {
        int n = wi * 64 + lane;
        if (n < NCOL) {
            const float4* br = (const float4*)(book + (size_t)n * EDIM);
            float c0 = 0.f, c1 = 0.f, c2 = 0.f, c3 = 0.f;
            #pragma unroll 8
            for (int k = 0; k < 64; k++) {
                float4 bo = br[k]; float4 za = zr[k];
                c0 = fmaf(za.x, bo.x, c0); c1 = fmaf(za.y, bo.y, c1);
                c2 = fmaf(za.z, bo.z, c2); c3 = fmaf(za.w, bo.w, c3);
            }
            float cr = (c0 + c1) + (c2 + c3);
            float d0 = (zsq + bsq[n]) - 2.0f * cr;     /* reference-style formation */
            if (d0 < best || (d0 == best && n < bidx)) { best = d0; bidx = n; }
        }
    }
    #pragma unroll
    for (int off = 32; off; off >>= 1) {
        float ob = __shfl_xor(best, off, 64);
        int   oi = __shfl_xor(bidx, off, 64);
        if (ob < best || (ob == best && oi < bidx)) { best = ob; bidx = oi; }
    }
    if (lane == 0) { sb[w] = best; si[w] = bidx; }
    __syncthreads();
    if (w != 0) return;

    best = sb[0]; bidx = si[0];
    for (int i = 1; i < 4; i++) {
        float vv = sb[i]; int ii = si[i];
        if (vv < best || (vv == best && ii < bidx)) { best = vv; bidx = ii; }
    }

    int ind = min(bidx, N_E - 1);
    int kk = 0;                              /* coe = kk * PERS */
    size_t ibase = (size_t)b * TT;
    if (lane == 0) wind[ibase] = ind;

    const float* eb = e + (size_t)b * TT * NPAD;
    const float QS = 1.0f / PERS;            /* 10240 */

    int _g = lane >> 5;                      /* row-in-pair */
    int _cl = lane & 31;                     /* col-in-window */

    DECLW                                    /* A{0,1}_{0..4}, q_{0..4} */

    int cbc = ind < 992 ? ind : 992;         /* base, chunk 0 */
    int cbn = cbc;                           /* base, chunk 1 (drift<=19 ok) */
    /* prologue: issue chunks 0 (rows 1-10) and 1 (rows 11-20) */
    { const float* _pe = eb + cbc + _cl; int _tb = 1;  LDSET(0) }
    { const float* _pe = eb + cbn + _cl; int _tb = 11; LDSET(1) }
    asm volatile("s_waitcnt vmcnt(5)" ::: "memory");   /* chunk 0 (+init store) done */
    __builtin_amdgcn_sched_barrier(0);
    { bool _capn = (cbc + _cl == 1023); QCSET(0) }     /* q for chunk 0 */

    int t = 1;
    #pragma unroll 1
    for (int cc = 0; cc < 52; cc++) {        /* 104 chunks of 10 rows (t>=1024 guarded) */
        ITERX(0, 1)
        ITERX(1, 0)
    }
}

/* ---------------- K3: per-row hinge-loss partial + z_q gather + idx emit ------ */
__global__ __launch_bounds__(256) void k3_loss_zq(const float* __restrict__ e,
                                                  const int* __restrict__ wind,
                                                  const float* __restrict__ book,
                                                  float* __restrict__ part,
                                                  float* __restrict__ out) {
    int rIdx = blockIdx.x, tid = threadIdx.x;
    int ind = wind[rIdx];
    const float* er = e + (size_t)rIdx * NPAD;
    float eind = er[ind];
    float p = 0.0f;
    for (int n = tid; n < NCOL; n += 256) {
        float v = eind - er[n] + EPSC;
        p += v > 0.0f ? v : 0.0f;
    }
    __shared__ float sd[256];
    sd[tid] = p; __syncthreads();
    for (int s = 128; s > 0; s >>= 1) { if (tid < s) sd[tid] += sd[tid + s]; __syncthreads(); }
    if (tid == 0) { part[rIdx] = sd[0]; out[OUT_IDX + rIdx] = (float)ind; }
    out[(size_t)rIdx * 256 + tid] = book[(size_t)ind * EDIM + tid];   /* z_q */
}

/* ---------------- K4: final loss reduce + v ---------------- */
__global__ __launch_bounds__(256) void k4_final(const float* __restrict__ part,
                                                const int* __restrict__ wind,
                                                float* __restrict__ out) {
    int tid = threadIdx.x;
    float s = 0.0f;
    for (int i = tid; i < NROW; i += 256) s += part[i];
    __shared__ float sd[256];
    sd[tid] = s; __syncthreads();
    for (int st = 128; st > 0; st >>= 1) { if (tid < st) sd[tid] += sd[tid + st]; __syncthreads(); }
    if (tid == 0) {
        int mn = wind[0], mx = wind[TT - 1];
        for (int b = 1; b < BB; b++) {
            mn = min(mn, wind[(size_t)b * TT]);
            mx = max(mx, wind[(size_t)b * TT + TT - 1]);
        }
        out[OUT_LOSS] = 1.25f * sd[0] / ((float)NROW * (float)NCOL);
        out[OUT_V] = (float)(mx - mn);
    }
}

extern "C" void kernel_launch(void* const* d_in, const int* in_sizes, int n_in,
                              void* d_out, int out_size, void* d_ws, size_t ws_size,
                              hipStream_t stream) {
    const float* z    = (const float*)d_in[0];
    const float* book = (const float*)d_in[1];
    char* ws = (char*)d_ws;
    unsigned short* zb = (unsigned short*)(ws + WS_ZB);
    unsigned short* bb = (unsigned short*)(ws + WS_BBF);
    float* bsq  = (float*)(ws + WS_BSQ);
    float* e    = (float*)(ws + WS_E);
    int*   wind = (int*)(ws + WS_IND);
    float* part = (float*)(ws + WS_PART);
    float* out  = (float*)d_out;

    hipLaunchKernelGGL(k0_prep,    dim3(4096 + 1152), dim3(256), 0, stream, z, book, zb, bb, bsq);
    hipLaunchKernelGGL(k1_gemm,    dim3(128, 9),      dim3(256), 0, stream, zb, bb, bsq, e);
    hipLaunchKernelGGL(k2_scan,    dim3(16),          dim3(256), 0, stream, z, book, bsq, e, wind);
    hipLaunchKernelGGL(k3_loss_zq, dim3(16384),       dim3(256), 0, stream, e, wind, book, part, out);
    hipLaunchKernelGGL(k4_final,   dim3(1),           dim3(256), 0, stream, part, wind, out);
}